// Round 4
// baseline (295.854 us; speedup 1.0000x reference)
//
#include <hip/hip_runtime.h>
#include <hip/hip_bf16.h>

#define N 2048
#define B 16

typedef float v4f __attribute__((ext_vector_type(4)));
typedef float v2f __attribute__((ext_vector_type(2)));

// Kernel 1: Asum[b,i] = sum_k |s[b,i] - s[b,k]|
// grid (N/128, B) = 256 blocks, 256 threads. Two threads per i, each sums
// half the k-range (wave-uniform LDS float4 broadcast reads), combine in LDS.
__global__ __launch_bounds__(256) void asum_kernel(const float* __restrict__ s,
                                                   float* __restrict__ asum) {
    const int b = blockIdx.y;
    const int chunk = blockIdx.x;  // 128 i's per block

    __shared__ float row[N];
    __shared__ float partial[256];
    const v4f* g4 = (const v4f*)(s + b * N);
    v4f* r4 = (v4f*)row;
    r4[threadIdx.x] = g4[threadIdx.x];
    r4[threadIdx.x + 256] = g4[threadIdx.x + 256];
    __syncthreads();

    const int il = threadIdx.x & 127;
    const int half = threadIdx.x >> 7;           // wave-uniform (waves 0,1 vs 2,3)
    const int i = chunk * 128 + il;
    const float si = row[i];
    const v4f* row4 = (const v4f*)(row + half * (N / 2));
    float acc = 0.0f;
#pragma unroll 4
    for (int k = 0; k < N / 8; ++k) {
        v4f rv = row4[k];
        acc += fabsf(si - rv.x) + fabsf(si - rv.y) +
               fabsf(si - rv.z) + fabsf(si - rv.w);
    }
    partial[threadIdx.x] = acc;
    __syncthreads();
    if (threadIdx.x < 128)
        asum[b * N + i] = partial[threadIdx.x] + partial[threadIdx.x + 128];
}

// Kernel 2: per-row stats. One wave per (b,j): m = max_i v, rZ = 1/sum exp(v-m),
// v_i = s_i*(2047-2j) - Asum_i. Writes mz[b*N+j] = {m, rZ}. 256 KB out.
__global__ __launch_bounds__(256) void rowstats_kernel(const float* __restrict__ s,
                                                       const float* __restrict__ asum,
                                                       v2f* __restrict__ mz) {
    const int t = threadIdx.x;
    const int lane = t & 63;
    const int wave = t >> 6;
    const int j = blockIdx.x * 4 + wave;
    const int b = blockIdx.y;

    const float cj = (float)(N - 1 - 2 * j);

    const v4f* s4 = (const v4f*)(s + (size_t)b * N);
    const v4f* a4 = (const v4f*)(asum + (size_t)b * N);

    float v[32];
#pragma unroll
    for (int c = 0; c < 8; ++c) {
        v4f sv = s4[c * 64 + lane];
        v4f av = a4[c * 64 + lane];
        v[c * 4 + 0] = sv.x * cj - av.x;
        v[c * 4 + 1] = sv.y * cj - av.y;
        v[c * 4 + 2] = sv.z * cj - av.z;
        v[c * 4 + 3] = sv.w * cj - av.w;
    }

    float m = v[0];
#pragma unroll
    for (int i = 1; i < 32; ++i) m = fmaxf(m, v[i]);
#pragma unroll
    for (int off = 32; off >= 1; off >>= 1)
        m = fmaxf(m, __shfl_xor(m, off));

    float sum = 0.0f;
#pragma unroll
    for (int i = 0; i < 32; ++i)
        sum += __expf(v[i] - m);
#pragma unroll
    for (int off = 32; off >= 1; off >>= 1)
        sum += __shfl_xor(sum, off);

    if (lane == 0) {
        v2f r;
        r.x = m;
        r.y = 1.0f / sum;
        mz[(size_t)b * N + j] = r;
    }
}

// Kernel 3: pure stream. out[b,j,i] = exp(s_i*cj - Asum_i - m) * rZ.
// Grid-stride over B*N*N/4 float4 chunks; no barriers, no shuffles, no LDS.
// 8 waves per row -> j is wave-uniform; s/a rows are L1-resident.
#define STREAM_BLOCKS 8192
__global__ __launch_bounds__(256) void stream_kernel(const float* __restrict__ s,
                                                     const float* __restrict__ asum,
                                                     const v2f* __restrict__ mz,
                                                     float* __restrict__ out) {
    const int tid = blockIdx.x * 256 + threadIdx.x;
    const int nth = STREAM_BLOCKS * 256;          // 2,097,152
    v4f* o4 = (v4f*)out;
    // total chunks = B*N*N/4 = 16,777,216 = nth * 8
#pragma unroll
    for (int it = 0; it < 8; ++it) {
        const int c = tid + it * nth;
        const int i4 = c & (N / 4 - 1);           // 0..511
        const int row = c >> 9;                   // b*N + j
        const int j = row & (N - 1);
        const int b = row >> 11;

        const v4f sv = ((const v4f*)(s + b * N))[i4];
        const v4f av = ((const v4f*)(asum + b * N))[i4];
        const v2f mr = mz[row];
        const float cj = (float)(N - 1 - 2 * j);
        const float mm = mr.x;
        const float rz = mr.y;

        v4f o;
        o.x = __expf(sv.x * cj - av.x - mm) * rz;
        o.y = __expf(sv.y * cj - av.y - mm) * rz;
        o.z = __expf(sv.z * cj - av.z - mm) * rz;
        o.w = __expf(sv.w * cj - av.w - mm) * rz;
        __builtin_nontemporal_store(o, &o4[c]);
    }
}

extern "C" void kernel_launch(void* const* d_in, const int* in_sizes, int n_in,
                              void* d_out, int out_size, void* d_ws, size_t ws_size,
                              hipStream_t stream) {
    const float* scores = (const float*)d_in[0];
    float* out = (float*)d_out;
    float* asum = (float*)d_ws;                  // B*N*4   = 128 KB
    v2f* mz = (v2f*)((char*)d_ws + B * N * 4);   // B*N*8   = 256 KB

    dim3 g1(N / 128, B);
    asum_kernel<<<g1, 256, 0, stream>>>(scores, asum);

    dim3 g2(N / 4, B);
    rowstats_kernel<<<g2, 256, 0, stream>>>(scores, asum, mz);

    stream_kernel<<<STREAM_BLOCKS, 256, 0, stream>>>(scores, asum, mz, out);
}

// Round 6
// 273.374 us; speedup vs baseline: 1.0822x; 1.0822x over previous
//
#include <hip/hip_runtime.h>
#include <hip/hip_bf16.h>

#define N 2048
#define B 16
#define LOG2E 1.44269504088896340736f

typedef float v4f __attribute__((ext_vector_type(4)));

// Kernel 1: asum2[b,i] = LOG2E * sum_k |s[b,i] - s[b,k]|
// grid (N/128, B), block 256. Two threads per i, each sums half the k-range
// via wave-uniform LDS float4 broadcast reads; combine through LDS.
__global__ __launch_bounds__(256) void asum_kernel(const float* __restrict__ s,
                                                   float* __restrict__ asum2) {
    const int b = blockIdx.y;
    const int chunk = blockIdx.x;

    __shared__ float row[N];
    __shared__ float partial[256];
    const v4f* g4 = (const v4f*)(s + b * N);
    v4f* r4 = (v4f*)row;
    r4[threadIdx.x] = g4[threadIdx.x];
    r4[threadIdx.x + 256] = g4[threadIdx.x + 256];
    __syncthreads();

    const int il = threadIdx.x & 127;
    const int half = threadIdx.x >> 7;   // wave-uniform
    const int i = chunk * 128 + il;
    const float si = row[i];
    const v4f* row4 = (const v4f*)(row + half * (N / 2));
    float acc = 0.0f;
#pragma unroll 4
    for (int k = 0; k < N / 8; ++k) {
        v4f rv = row4[k];
        acc += fabsf(si - rv.x) + fabsf(si - rv.y) +
               fabsf(si - rv.z) + fabsf(si - rv.w);
    }
    partial[threadIdx.x] = acc;
    __syncthreads();
    if (threadIdx.x < 128)
        asum2[b * N + i] = LOG2E * (partial[threadIdx.x] + partial[threadIdx.x + 128]);
}

// Kernel 2: ONE WAVE per output row (b, j). No barriers, no LDS.
// u_i = s_i * (cj*LOG2E) - asum2_i ;  out = 2^(u_i - max) / sum 2^(u - max).
// Each lane owns 32 elements as 8 float4 chunks (coalesced 16B/lane).
// grid = (N/4, B), block = 256 (4 waves -> 4 consecutive j per block).
__global__ __launch_bounds__(256) void softmax_rows(const float* __restrict__ s,
                                                    const float* __restrict__ asum2,
                                                    float* __restrict__ out) {
    const int t = threadIdx.x;
    const int lane = t & 63;
    const int wave = t >> 6;
    const int j = blockIdx.x * 4 + wave;
    const int b = blockIdx.y;

    const float cj = (float)(N - 1 - 2 * j) * LOG2E;

    const v4f* s4 = (const v4f*)(s + (size_t)b * N);
    const v4f* a4 = (const v4f*)(asum2 + (size_t)b * N);

    float v[32];
#pragma unroll
    for (int c = 0; c < 8; ++c) {
        v4f sv = s4[c * 64 + lane];
        v4f av = a4[c * 64 + lane];
        v[c * 4 + 0] = sv.x * cj - av.x;
        v[c * 4 + 1] = sv.y * cj - av.y;
        v[c * 4 + 2] = sv.z * cj - av.z;
        v[c * 4 + 3] = sv.w * cj - av.w;
    }

    // wave-level max reduction (width 64)
    float m = v[0];
#pragma unroll
    for (int i = 1; i < 32; ++i) m = fmaxf(m, v[i]);
#pragma unroll
    for (int off = 32; off >= 1; off >>= 1)
        m = fmaxf(m, __shfl_xor(m, off));

    // exp2 + wave-level sum reduction (bare v_exp_f32, no mul)
    float sum = 0.0f;
#pragma unroll
    for (int i = 0; i < 32; ++i) {
        v[i] = __builtin_amdgcn_exp2f(v[i] - m);
        sum += v[i];
    }
#pragma unroll
    for (int off = 32; off >= 1; off >>= 1)
        sum += __shfl_xor(sum, off);

    const float r = 1.0f / sum;

    v4f* o4 = (v4f*)(out + ((size_t)b * N + j) * N);
#pragma unroll
    for (int c = 0; c < 8; ++c) {
        v4f o;
        o.x = v[c * 4 + 0] * r;
        o.y = v[c * 4 + 1] * r;
        o.z = v[c * 4 + 2] * r;
        o.w = v[c * 4 + 3] * r;
        __builtin_nontemporal_store(o, &o4[c * 64 + lane]);
    }
}

extern "C" void kernel_launch(void* const* d_in, const int* in_sizes, int n_in,
                              void* d_out, int out_size, void* d_ws, size_t ws_size,
                              hipStream_t stream) {
    const float* scores = (const float*)d_in[0];
    float* out = (float*)d_out;
    float* asum2 = (float*)d_ws;   // B*N*4 = 128 KB

    dim3 g1(N / 128, B);
    asum_kernel<<<g1, 256, 0, stream>>>(scores, asum2);

    dim3 g2(N / 4, B);
    softmax_rows<<<g2, 256, 0, stream>>>(scores, asum2, out);
}

// Round 7
// 272.045 us; speedup vs baseline: 1.0875x; 1.0049x over previous
//
#include <hip/hip_runtime.h>
#include <hip/hip_bf16.h>

#define N 2048
#define B 16
#define LOG2E 1.44269504088896340736f

typedef float v4f __attribute__((ext_vector_type(4)));

// Kernel 1: asum2[b,i] = LOG2E * sum_k |s[b,i] - s[b,k]|
// grid (N/128, B), block 256. Two threads per i, each sums half the k-range
// via wave-uniform LDS float4 broadcast reads; combine through LDS.
__global__ __launch_bounds__(256) void asum_kernel(const float* __restrict__ s,
                                                   float* __restrict__ asum2) {
    const int b = blockIdx.y;
    const int chunk = blockIdx.x;

    __shared__ float row[N];
    __shared__ float partial[256];
    const v4f* g4 = (const v4f*)(s + b * N);
    v4f* r4 = (v4f*)row;
    r4[threadIdx.x] = g4[threadIdx.x];
    r4[threadIdx.x + 256] = g4[threadIdx.x + 256];
    __syncthreads();

    const int il = threadIdx.x & 127;
    const int half = threadIdx.x >> 7;   // wave-uniform
    const int i = chunk * 128 + il;
    const float si = row[i];
    const v4f* row4 = (const v4f*)(row + half * (N / 2));
    float acc = 0.0f;
#pragma unroll 4
    for (int k = 0; k < N / 8; ++k) {
        v4f rv = row4[k];
        acc += fabsf(si - rv.x) + fabsf(si - rv.y) +
               fabsf(si - rv.z) + fabsf(si - rv.w);
    }
    partial[threadIdx.x] = acc;
    __syncthreads();
    if (threadIdx.x < 128)
        asum2[b * N + i] = LOG2E * (partial[threadIdx.x] + partial[threadIdx.x + 128]);
}

// Kernel 2: 4 rows per block (one per wave), s/asum2 rows staged in LDS ONCE
// per block -> global read traffic cut 8x (1 GiB -> 128 MB of L2 reads).
// Per wave: u_i = (s_i*LOG2E)*cjraw - asum2_i; out = 2^(u-max) / sum.
// Each lane owns 32 elements as 8 v4f chunks; conflict-free ds_read_b128.
__global__ __launch_bounds__(256) void softmax_rows(const float* __restrict__ s,
                                                    const float* __restrict__ asum2,
                                                    float* __restrict__ out) {
    __shared__ float ls[N];   // s * LOG2E
    __shared__ float la[N];   // asum2 (already has LOG2E folded)

    const int t = threadIdx.x;
    const int lane = t & 63;
    const int wave = t >> 6;
    const int b = blockIdx.y;
    const int j = blockIdx.x * 4 + wave;

    // cooperative staging: 256 threads x 2 v4f per array
    {
        const v4f* g4 = (const v4f*)(s + (size_t)b * N);
        const v4f* ga4 = (const v4f*)(asum2 + (size_t)b * N);
        v4f* l4 = (v4f*)ls;
        v4f* m4 = (v4f*)la;
        v4f s0 = g4[t], s1 = g4[t + 256];
        v4f a0 = ga4[t], a1 = ga4[t + 256];
        s0 *= LOG2E; s1 *= LOG2E;
        l4[t] = s0; l4[t + 256] = s1;
        m4[t] = a0; m4[t + 256] = a1;
    }
    __syncthreads();

    const float cj = (float)(N - 1 - 2 * j);  // scaling[j] (LOG2E already in ls/la)

    const v4f* ls4 = (const v4f*)ls;
    const v4f* la4 = (const v4f*)la;

    float v[32];
#pragma unroll
    for (int c = 0; c < 8; ++c) {
        v4f sv = ls4[c * 64 + lane];
        v4f av = la4[c * 64 + lane];
        v[c * 4 + 0] = sv.x * cj - av.x;
        v[c * 4 + 1] = sv.y * cj - av.y;
        v[c * 4 + 2] = sv.z * cj - av.z;
        v[c * 4 + 3] = sv.w * cj - av.w;
    }

    // wave-level max reduction (width 64)
    float m = v[0];
#pragma unroll
    for (int i = 1; i < 32; ++i) m = fmaxf(m, v[i]);
#pragma unroll
    for (int off = 32; off >= 1; off >>= 1)
        m = fmaxf(m, __shfl_xor(m, off));

    // exp2 + wave-level sum reduction (bare v_exp_f32)
    float sum = 0.0f;
#pragma unroll
    for (int i = 0; i < 32; ++i) {
        v[i] = __builtin_amdgcn_exp2f(v[i] - m);
        sum += v[i];
    }
#pragma unroll
    for (int off = 32; off >= 1; off >>= 1)
        sum += __shfl_xor(sum, off);

    const float r = 1.0f / sum;

    v4f* o4 = (v4f*)(out + ((size_t)b * N + j) * N);
#pragma unroll
    for (int c = 0; c < 8; ++c) {
        v4f o;
        o.x = v[c * 4 + 0] * r;
        o.y = v[c * 4 + 1] * r;
        o.z = v[c * 4 + 2] * r;
        o.w = v[c * 4 + 3] * r;
        __builtin_nontemporal_store(o, &o4[c * 64 + lane]);
    }
}

extern "C" void kernel_launch(void* const* d_in, const int* in_sizes, int n_in,
                              void* d_out, int out_size, void* d_ws, size_t ws_size,
                              hipStream_t stream) {
    const float* scores = (const float*)d_in[0];
    float* out = (float*)d_out;
    float* asum2 = (float*)d_ws;   // B*N*4 = 128 KB

    dim3 g1(N / 128, B);
    asum_kernel<<<g1, 256, 0, stream>>>(scores, asum2);

    dim3 g2(N / 4, B);
    softmax_rows<<<g2, 256, 0, stream>>>(scores, asum2, out);
}

// Round 8
// 261.920 us; speedup vs baseline: 1.1296x; 1.0387x over previous
//
#include <hip/hip_runtime.h>
#include <hip/hip_bf16.h>

#define N 2048
#define B 16
#define LOG2E 1.44269504088896340736f

typedef float v4f __attribute__((ext_vector_type(4)));

// Kernel 1: asum2[b,i] = LOG2E * sum_k |s[b,i] - s[b,k]|
__global__ __launch_bounds__(256) void asum_kernel(const float* __restrict__ s,
                                                   float* __restrict__ asum2) {
    const int b = blockIdx.y;
    const int chunk = blockIdx.x;

    __shared__ float row[N];
    __shared__ float partial[256];
    const v4f* g4 = (const v4f*)(s + b * N);
    v4f* r4 = (v4f*)row;
    r4[threadIdx.x] = g4[threadIdx.x];
    r4[threadIdx.x + 256] = g4[threadIdx.x + 256];
    __syncthreads();

    const int il = threadIdx.x & 127;
    const int half = threadIdx.x >> 7;   // wave-uniform
    const int i = chunk * 128 + il;
    const float si = row[i];
    const v4f* row4 = (const v4f*)(row + half * (N / 2));
    float acc = 0.0f;
#pragma unroll 4
    for (int k = 0; k < N / 8; ++k) {
        v4f rv = row4[k];
        acc += fabsf(si - rv.x) + fabsf(si - rv.y) +
               fabsf(si - rv.z) + fabsf(si - rv.w);
    }
    partial[threadIdx.x] = acc;
    __syncthreads();
    if (threadIdx.x < 128)
        asum2[b * N + i] = LOG2E * (partial[threadIdx.x] + partial[threadIdx.x + 128]);
}

// Kernel 2: 8 rows per block; each wave processes TWO independent rows
// (jA = base+wave, jB = base+wave+4) interleaved for ILP — row B's fma/exp
// fills row A's shuffle-latency bubbles. s/asum2 staged in LDS once per
// 8 rows. grid = (N/8, B), block = 256.
__global__ __launch_bounds__(256) void softmax_rows(const float* __restrict__ s,
                                                    const float* __restrict__ asum2,
                                                    float* __restrict__ out) {
    __shared__ float ls[N];   // s * LOG2E
    __shared__ float la[N];   // asum2 (LOG2E already folded)

    const int t = threadIdx.x;
    const int lane = t & 63;
    const int wave = t >> 6;
    const int b = blockIdx.y;
    const int jA = blockIdx.x * 8 + wave;
    const int jB = jA + 4;

    {
        const v4f* g4 = (const v4f*)(s + (size_t)b * N);
        const v4f* ga4 = (const v4f*)(asum2 + (size_t)b * N);
        v4f* l4 = (v4f*)ls;
        v4f* m4 = (v4f*)la;
        v4f s0 = g4[t], s1 = g4[t + 256];
        v4f a0 = ga4[t], a1 = ga4[t + 256];
        s0 *= LOG2E; s1 *= LOG2E;
        l4[t] = s0; l4[t + 256] = s1;
        m4[t] = a0; m4[t + 256] = a1;
    }
    __syncthreads();

    const float cA = (float)(N - 1 - 2 * jA);
    const float cB = (float)(N - 1 - 2 * jB);

    const v4f* ls4 = (const v4f*)ls;
    const v4f* la4 = (const v4f*)la;

    float va[32], vb[32];
#pragma unroll
    for (int c = 0; c < 8; ++c) {
        v4f sv = ls4[c * 64 + lane];
        v4f av = la4[c * 64 + lane];
        va[c * 4 + 0] = sv.x * cA - av.x;  vb[c * 4 + 0] = sv.x * cB - av.x;
        va[c * 4 + 1] = sv.y * cA - av.y;  vb[c * 4 + 1] = sv.y * cB - av.y;
        va[c * 4 + 2] = sv.z * cA - av.z;  vb[c * 4 + 2] = sv.z * cB - av.z;
        va[c * 4 + 3] = sv.w * cA - av.w;  vb[c * 4 + 3] = sv.w * cB - av.w;
    }

    // interleaved max reductions
    float mA = va[0], mB = vb[0];
#pragma unroll
    for (int i = 1; i < 32; ++i) { mA = fmaxf(mA, va[i]); mB = fmaxf(mB, vb[i]); }
#pragma unroll
    for (int off = 32; off >= 1; off >>= 1) {
        mA = fmaxf(mA, __shfl_xor(mA, off));
        mB = fmaxf(mB, __shfl_xor(mB, off));
    }

    // interleaved exp2 + sum reductions
    float sA = 0.0f, sB = 0.0f;
#pragma unroll
    for (int i = 0; i < 32; ++i) {
        va[i] = __builtin_amdgcn_exp2f(va[i] - mA);  sA += va[i];
        vb[i] = __builtin_amdgcn_exp2f(vb[i] - mB);  sB += vb[i];
    }
#pragma unroll
    for (int off = 32; off >= 1; off >>= 1) {
        sA += __shfl_xor(sA, off);
        sB += __shfl_xor(sB, off);
    }

    const float rA = 1.0f / sA;
    const float rB = 1.0f / sB;

    v4f* oA = (v4f*)(out + ((size_t)b * N + jA) * N);
    v4f* oB = (v4f*)(out + ((size_t)b * N + jB) * N);
#pragma unroll
    for (int c = 0; c < 8; ++c) {
        v4f o;
        o.x = va[c * 4 + 0] * rA; o.y = va[c * 4 + 1] * rA;
        o.z = va[c * 4 + 2] * rA; o.w = va[c * 4 + 3] * rA;
        oA[c * 64 + lane] = o;
        v4f p;
        p.x = vb[c * 4 + 0] * rB; p.y = vb[c * 4 + 1] * rB;
        p.z = vb[c * 4 + 2] * rB; p.w = vb[c * 4 + 3] * rB;
        oB[c * 64 + lane] = p;
    }
}

extern "C" void kernel_launch(void* const* d_in, const int* in_sizes, int n_in,
                              void* d_out, int out_size, void* d_ws, size_t ws_size,
                              hipStream_t stream) {
    const float* scores = (const float*)d_in[0];
    float* out = (float*)d_out;
    float* asum2 = (float*)d_ws;   // B*N*4 = 128 KB

    dim3 g1(N / 128, B);
    asum_kernel<<<g1, 256, 0, stream>>>(scores, asum2);

    dim3 g2(N / 8, B);
    softmax_rows<<<g2, 256, 0, stream>>>(scores, asum2, out);
}